// Round 3
// baseline (3061.586 us; speedup 1.0000x reference)
//
#include <hip/hip_runtime.h>
#include <hip/hip_bf16.h>

#define N_NODES 100000
#define N_EDGES 3200000

typedef __hip_bfloat16 bf16;

// ---- dtype-flexible load: flag==1 -> f32, flag==0 -> bf16 ----
__device__ __forceinline__ float loadF(const void* p, long long i, int isf32) {
    if (isf32) return ((const float*)p)[i];
    unsigned short v = ((const unsigned short*)p)[i];
    union { unsigned u; float f; } c;
    c.u = ((unsigned)v) << 16;
    return c.f;
}

// ---- weight canonical layout (float offsets inside wts) ----
#define W_GAMMA 0
#define W_BETA 8
#define W_C1PW 16
#define W_C1PB 48
#define W_C1LW 56
#define W_C1LB 376
#define W_C1RW 440
#define W_C2PW 760
#define W_C2PB 4856
#define W_C2LW 4920
#define W_C2LB 9016
#define W_C2RW 9080
#define W_C3PW 13176
#define W_C3PB 17272
#define W_C3LW 17336
#define W_C3LB 17656
#define W_C3RW 17664

// ---------------- dtype detection ----------------
__global__ void detect_dtype(const void* ew, int* flag) {
    const unsigned short* u = (const unsigned short*)ew;
    int lane = threadIdx.x;
    int big = 0;
    for (int i = lane; i < 1024; i += 64) {
        unsigned short v = u[2 * i];
        int ex = (v >> 7) & 0xFF;
        if (ex >= 128) big++;
    }
#pragma unroll
    for (int o = 32; o; o >>= 1) big += __shfl_xor(big, o, 64);
    if (lane == 0) *flag = (big > 100) ? 1 : 0;
}

// ---------------- convert all weight tensors to canonical fp32 ----------------
__global__ void cvt_weights(const int* flag,
                            const void* p0, const void* p1, const void* p2, const void* p3,
                            const void* p4, const void* p5, const void* p6, const void* p7,
                            const void* p8, const void* p9, const void* p10, const void* p11,
                            const void* p12, const void* p13, const void* p14, const void* p15,
                            const void* p16, float* __restrict__ wts) {
    const void* ptrs[17] = {p0, p1, p2, p3, p4, p5, p6, p7, p8,
                            p9, p10, p11, p12, p13, p14, p15, p16};
    const int sz[17] = {5, 5, 25, 5, 320, 64, 320, 4096, 64,
                        4096, 64, 4096, 4096, 64, 320, 5, 320};
    const int off[17] = {W_GAMMA, W_BETA, W_C1PW, W_C1PB, W_C1LW, W_C1LB, W_C1RW,
                         W_C2PW, W_C2PB, W_C2LW, W_C2LB, W_C2RW,
                         W_C3PW, W_C3PB, W_C3LW, W_C3LB, W_C3RW};
    int t = blockIdx.x;
    int isf32 = *flag;
    for (int i = threadIdx.x; i < sz[t]; i += blockDim.x)
        wts[off[t] + i] = loadF(ptrs[t], i, isf32);
}

// ---------------- BN statistics ----------------
__global__ void bn_stats(const void* __restrict__ h, const int* __restrict__ flag,
                         float* __restrict__ stats) {
    int isf32 = *flag;
    float s[5] = {0, 0, 0, 0, 0}, q[5] = {0, 0, 0, 0, 0};
    int tid = blockIdx.x * blockDim.x + threadIdx.x;
    int stride = gridDim.x * blockDim.x;
    for (int i = tid; i < N_NODES; i += stride) {
#pragma unroll
        for (int f = 0; f < 5; f++) {
            float v = loadF(h, i * 5 + f, isf32);
            s[f] += v;
            q[f] += v * v;
        }
    }
#pragma unroll
    for (int f = 0; f < 5; f++) {
#pragma unroll
        for (int o = 32; o; o >>= 1) {
            s[f] += __shfl_xor(s[f], o, 64);
            q[f] += __shfl_xor(q[f], o, 64);
        }
    }
    __shared__ float ls[4][10];
    int wave = threadIdx.x >> 6, lane = threadIdx.x & 63;
    if (lane == 0) {
#pragma unroll
        for (int f = 0; f < 5; f++) { ls[wave][f] = s[f]; ls[wave][5 + f] = q[f]; }
    }
    __syncthreads();
    if (threadIdx.x < 10) {
        float v = ls[0][threadIdx.x] + ls[1][threadIdx.x] + ls[2][threadIdx.x] + ls[3][threadIdx.x];
        int idx = (threadIdx.x < 5) ? threadIdx.x : (threadIdx.x - 5 + 8);
        atomicAdd(&stats[idx], v);
    }
}

// stats[0..4]=sum, stats[8..12]=sumsq -> stats[16..20]=scale, stats[24..28]=bias
__global__ void bn_finalize(float* __restrict__ stats, const float* __restrict__ wts) {
    int f = threadIdx.x;
    if (f < 5) {
        float mean = stats[f] / (float)N_NODES;
        float var = stats[8 + f] / (float)N_NODES - mean * mean;
        float sc = wts[W_GAMMA + f] * rsqrtf(var + 1e-5f);
        stats[16 + f] = sc;
        stats[24 + f] = wts[W_BETA + f] - mean * sc;
    }
}

// ---------------- BN apply + conv1 projection (5->5) ----------------
__global__ void bn_proj1(const void* __restrict__ h, const int* __restrict__ flag,
                         const float* __restrict__ stats, const float* __restrict__ wts,
                         float* __restrict__ xbn, float* __restrict__ xp1) {
    int isf32 = *flag;
    int i = blockIdx.x * blockDim.x + threadIdx.x;
    if (i >= N_NODES) return;
    float x[5];
#pragma unroll
    for (int f = 0; f < 5; f++)
        x[f] = loadF(h, i * 5 + f, isf32) * stats[16 + f] + stats[24 + f];
#pragma unroll
    for (int f = 0; f < 5; f++) xbn[i * 5 + f] = x[f];
#pragma unroll
    for (int j = 0; j < 5; j++) {
        float a = wts[W_C1PB + j];
#pragma unroll
        for (int k = 0; k < 5; k++) a += x[k] * wts[W_C1PW + k * 5 + j];
        xp1[i * 5 + j] = fmaxf(a, 0.f);
    }
}

// ---------------- degree count ----------------
__global__ void degree_kernel(const int* __restrict__ dst, float* __restrict__ cnt) {
    int e = blockIdx.x * blockDim.x + threadIdx.x;
    if (e < N_EDGES) atomicAdd(&cnt[dst[e]], 1.0f);
}

// ---------------- 5-wide edge scatter (conv1, conv3) ----------------
__global__ void scatter5(const int* __restrict__ src, const int* __restrict__ dst,
                         const void* __restrict__ ew, const int* __restrict__ flag,
                         const float* __restrict__ y, float* __restrict__ agg) {
    int isf32 = *flag;
    int e = blockIdx.x * blockDim.x + threadIdx.x;
    if (e >= N_EDGES) return;
    int s = src[e], d = dst[e];
    float w = loadF(ew, e, isf32);
#pragma unroll
    for (int f = 0; f < 5; f++) atomicAdd(&agg[d * 5 + f], y[s * 5 + f] * w);
}

// ---------------- 64-wide edge scatter (conv2): one wave per edge ----------------
__global__ void __launch_bounds__(256) scatter64(const int* __restrict__ src,
                                                 const int* __restrict__ dst,
                                                 const void* __restrict__ ew,
                                                 const int* __restrict__ flag,
                                                 const float* __restrict__ y,
                                                 float* __restrict__ agg) {
    int isf32 = *flag;
    int wid = (blockIdx.x * blockDim.x + threadIdx.x) >> 6;
    int lane = threadIdx.x & 63;
    if (wid >= N_EDGES) return;
    int s = src[wid], d = dst[wid];
    float w = loadF(ew, wid, isf32);
    float v = y[s * 64 + lane] * w;
    atomicAdd(&agg[d * 64 + lane], v);
}

// ---------------- conv1 epilogue ----------------
__global__ void __launch_bounds__(256) epilogue1(const float* __restrict__ agg,
                                                 const float* __restrict__ cnt,
                                                 const float* __restrict__ xbn,
                                                 const float* __restrict__ wts,
                                                 float* __restrict__ x1) {
    __shared__ float s_lw[5 * 64], s_rw[5 * 64], s_lb[64];
    for (int t = threadIdx.x; t < 320; t += 256) {
        s_lw[t] = wts[W_C1LW + t];
        s_rw[t] = wts[W_C1RW + t];
    }
    if (threadIdx.x < 64) s_lb[threadIdx.x] = wts[W_C1LB + threadIdx.x];
    __syncthreads();
    int wave = threadIdx.x >> 6, lane = threadIdx.x & 63;
    int node = blockIdx.x * 4 + wave;
    if (node >= N_NODES) return;
    float ic = 1.f / fmaxf(cnt[node], 1.f);
    float out = s_lb[lane];
#pragma unroll
    for (int k = 0; k < 5; k++) {
        float m = agg[node * 5 + k] * ic;
        float xb = xbn[node * 5 + k];
        out += m * s_lw[k * 64 + lane] + xb * s_rw[k * 64 + lane];
    }
    float ss = out * out;
#pragma unroll
    for (int o = 32; o; o >>= 1) ss += __shfl_xor(ss, o, 64);
    float v = out / fmaxf(sqrtf(ss), 1e-12f);
    x1[node * 64 + lane] = fmaxf(v, 0.f);
}

// ---------------- conv2 projection: y2 = relu(x1@pw2+pb2) @ lw2 ----------------
__global__ void __launch_bounds__(256) proj2(const float* __restrict__ x1,
                                             const float* __restrict__ wts,
                                             float* __restrict__ y2) {
    __shared__ float s_pw[64 * 64], s_lw[64 * 64], s_pb[64];
    for (int t = threadIdx.x; t < 4096; t += 256) {
        s_pw[t] = wts[W_C2PW + t];
        s_lw[t] = wts[W_C2LW + t];
    }
    if (threadIdx.x < 64) s_pb[threadIdx.x] = wts[W_C2PB + threadIdx.x];
    __syncthreads();
    int wave = threadIdx.x >> 6, lane = threadIdx.x & 63;
    int node = blockIdx.x * 4 + wave;
    if (node >= N_NODES) return;
    float xv = x1[node * 64 + lane];
    float a0 = s_pb[lane];
#pragma unroll
    for (int k = 0; k < 64; k++) a0 += __shfl(xv, k, 64) * s_pw[k * 64 + lane];
    float xp = fmaxf(a0, 0.f);
    float a1 = 0.f;
#pragma unroll
    for (int k = 0; k < 64; k++) a1 += __shfl(xp, k, 64) * s_lw[k * 64 + lane];
    y2[node * 64 + lane] = a1;
}

// ---------------- conv2 epilogue (x2 may alias x1: per-thread read-then-write same idx) ----
__global__ void __launch_bounds__(256) epilogue2(const float* __restrict__ agg,
                                                 const float* __restrict__ cnt,
                                                 const float* __restrict__ x1,
                                                 const float* __restrict__ wts,
                                                 float* __restrict__ x2) {
    __shared__ float s_rw[64 * 64], s_lb[64];
    for (int t = threadIdx.x; t < 4096; t += 256) s_rw[t] = wts[W_C2RW + t];
    if (threadIdx.x < 64) s_lb[threadIdx.x] = wts[W_C2LB + threadIdx.x];
    __syncthreads();
    int wave = threadIdx.x >> 6, lane = threadIdx.x & 63;
    int node = blockIdx.x * 4 + wave;
    if (node >= N_NODES) return;
    float ic = 1.f / fmaxf(cnt[node], 1.f);
    float xv = x1[node * 64 + lane];
    float out = agg[node * 64 + lane] * ic + s_lb[lane];
#pragma unroll
    for (int k = 0; k < 64; k++) out += __shfl(xv, k, 64) * s_rw[k * 64 + lane];
    float ss = out * out;
#pragma unroll
    for (int o = 32; o; o >>= 1) ss += __shfl_xor(ss, o, 64);
    float v = out / fmaxf(sqrtf(ss), 1e-12f);
    x2[node * 64 + lane] = fmaxf(v, 0.f);
}

// ---------------- conv3 projection: y3 = relu(x2@pw3+pb3) @ lw3 (64->5) ----------------
__global__ void __launch_bounds__(256) proj3(const float* __restrict__ x2,
                                             const float* __restrict__ wts,
                                             float* __restrict__ y3) {
    __shared__ float s_pw[64 * 64], s_lw[64 * 5], s_pb[64];
    for (int t = threadIdx.x; t < 4096; t += 256) s_pw[t] = wts[W_C3PW + t];
    for (int t = threadIdx.x; t < 320; t += 256) s_lw[t] = wts[W_C3LW + t];
    if (threadIdx.x < 64) s_pb[threadIdx.x] = wts[W_C3PB + threadIdx.x];
    __syncthreads();
    int wave = threadIdx.x >> 6, lane = threadIdx.x & 63;
    int node = blockIdx.x * 4 + wave;
    if (node >= N_NODES) return;
    float xv = x2[node * 64 + lane];
    float a = s_pb[lane];
#pragma unroll
    for (int k = 0; k < 64; k++) a += __shfl(xv, k, 64) * s_pw[k * 64 + lane];
    float xp = fmaxf(a, 0.f);
#pragma unroll
    for (int j = 0; j < 5; j++) {
        float p = xp * s_lw[lane * 5 + j];
#pragma unroll
        for (int o = 32; o; o >>= 1) p += __shfl_xor(p, o, 64);
        if (lane == j) y3[node * 5 + j] = p;
    }
}

// ---------------- conv3 epilogue (no relu), dtype-flexible output ----------------
__global__ void __launch_bounds__(256) epilogue3(const float* __restrict__ agg,
                                                 const float* __restrict__ cnt,
                                                 const float* __restrict__ x2,
                                                 const float* __restrict__ wts,
                                                 const int* __restrict__ flag,
                                                 void* __restrict__ outp) {
    __shared__ float s_rw[64 * 5];
    for (int t = threadIdx.x; t < 320; t += 256) s_rw[t] = wts[W_C3RW + t];
    __syncthreads();
    int isf32 = *flag;
    int wave = threadIdx.x >> 6, lane = threadIdx.x & 63;
    int node = blockIdx.x * 4 + wave;
    if (node >= N_NODES) return;
    float ic = 1.f / fmaxf(cnt[node], 1.f);
    float xv = x2[node * 64 + lane];
    float r[5];
#pragma unroll
    for (int j = 0; j < 5; j++) {
        float p = xv * s_rw[lane * 5 + j];
#pragma unroll
        for (int o = 32; o; o >>= 1) p += __shfl_xor(p, o, 64);
        r[j] = p + agg[node * 5 + j] * ic + wts[W_C3LB + j];
    }
    float ss = 0.f;
#pragma unroll
    for (int j = 0; j < 5; j++) ss += r[j] * r[j];
    float inv = 1.f / fmaxf(sqrtf(ss), 1e-12f);
#pragma unroll
    for (int j = 0; j < 5; j++) {
        if (lane == j) {
            float v = r[j] * inv;
            if (isf32) ((float*)outp)[node * 5 + j] = v;
            else ((bf16*)outp)[node * 5 + j] = __float2bfloat16(v);
        }
    }
}

extern "C" void kernel_launch(void* const* d_in, const int* in_sizes, int n_in,
                              void* d_out, int out_size, void* d_ws, size_t ws_size,
                              hipStream_t stream) {
    const void* h = d_in[0];
    const int* ei = (const int*)d_in[1];
    const int* src = ei;
    const int* dst = ei + N_EDGES;
    const void* ew = d_in[2];

    float* W = (float*)d_ws;
    int* flag = (int*)W;                    // [0]
    float* stats = W + 16;                  // 32 floats
    float* wts = W + 64;                    // ~18k floats
    float* xbn = W + 20480;                 // N*5
    float* xp1 = xbn + N_NODES * 5;         // N*5
    float* cnt = xp1 + N_NODES * 5;         // N
    float* agg = cnt + N_NODES;             // N*64 (reused per conv)
    float* x1 = agg + (size_t)N_NODES * 64; // N*64 f32
    float* y2 = x1 + (size_t)N_NODES * 64;  // N*64 f32
    float* x2 = x1;                         // alias: epilogue2 reads/writes same idx per-thread
    float* y3 = y2 + (size_t)N_NODES * 64;  // N*5 f32

    detect_dtype<<<1, 64, 0, stream>>>(ew, flag);
    cvt_weights<<<17, 256, 0, stream>>>(flag,
        d_in[3], d_in[4],                                   // gamma, beta
        d_in[5], d_in[6], d_in[7], d_in[8], d_in[9],        // c1
        d_in[10], d_in[11], d_in[12], d_in[13], d_in[14],   // c2
        d_in[15], d_in[16], d_in[17], d_in[18], d_in[19],   // c3
        wts);

    hipMemsetAsync(stats, 0, 32 * sizeof(float), stream);
    hipMemsetAsync(cnt, 0, N_NODES * sizeof(float), stream);
    hipMemsetAsync(agg, 0, N_NODES * 5 * sizeof(float), stream);

    bn_stats<<<200, 256, 0, stream>>>(h, flag, stats);
    bn_finalize<<<1, 64, 0, stream>>>(stats, wts);
    bn_proj1<<<(N_NODES + 255) / 256, 256, 0, stream>>>(h, flag, stats, wts, xbn, xp1);
    degree_kernel<<<(N_EDGES + 255) / 256, 256, 0, stream>>>(dst, cnt);
    scatter5<<<(N_EDGES + 255) / 256, 256, 0, stream>>>(src, dst, ew, flag, xp1, agg);
    epilogue1<<<N_NODES / 4, 256, 0, stream>>>(agg, cnt, xbn, wts, x1);

    hipMemsetAsync(agg, 0, (size_t)N_NODES * 64 * sizeof(float), stream);
    proj2<<<N_NODES / 4, 256, 0, stream>>>(x1, wts, y2);
    scatter64<<<N_EDGES / 4, 256, 0, stream>>>(src, dst, ew, flag, y2, agg);
    epilogue2<<<N_NODES / 4, 256, 0, stream>>>(agg, cnt, x1, wts, x2);

    hipMemsetAsync(agg, 0, N_NODES * 5 * sizeof(float), stream);
    proj3<<<N_NODES / 4, 256, 0, stream>>>(x2, wts, y3);
    scatter5<<<(N_EDGES + 255) / 256, 256, 0, stream>>>(src, dst, ew, flag, y3, agg);
    epilogue3<<<N_NODES / 4, 256, 0, stream>>>(agg, cnt, x2, wts, flag, d_out);
}

// Round 4
// 1087.079 us; speedup vs baseline: 2.8163x; 2.8163x over previous
//
#include <hip/hip_runtime.h>
#include <hip/hip_bf16.h>

#define N_NODES 100000
#define N_EDGES 3200000

typedef __hip_bfloat16 bf16;

// ---- dtype-flexible load: flag==1 -> f32, flag==0 -> bf16 ----
__device__ __forceinline__ float loadF(const void* p, long long i, int isf32) {
    if (isf32) return ((const float*)p)[i];
    unsigned short v = ((const unsigned short*)p)[i];
    union { unsigned u; float f; } c;
    c.u = ((unsigned)v) << 16;
    return c.f;
}

// ---- weight canonical layout (float offsets inside wts) ----
#define W_GAMMA 0
#define W_BETA 8
#define W_C1PW 16
#define W_C1PB 48
#define W_C1LW 56
#define W_C1LB 376
#define W_C1RW 440
#define W_C2PW 760
#define W_C2PB 4856
#define W_C2LW 4920
#define W_C2LB 9016
#define W_C2RW 9080
#define W_C3PW 13176
#define W_C3PB 17272
#define W_C3LW 17336
#define W_C3LB 17656
#define W_C3RW 17664

// ---------------- dtype detection ----------------
__global__ void detect_dtype(const void* ew, int* flag) {
    const unsigned short* u = (const unsigned short*)ew;
    int lane = threadIdx.x;
    int big = 0;
    for (int i = lane; i < 1024; i += 64) {
        unsigned short v = u[2 * i];
        int ex = (v >> 7) & 0xFF;
        if (ex >= 128) big++;
    }
#pragma unroll
    for (int o = 32; o; o >>= 1) big += __shfl_xor(big, o, 64);
    if (lane == 0) *flag = (big > 100) ? 1 : 0;
}

// ---------------- convert all weight tensors to canonical fp32 ----------------
__global__ void cvt_weights(const int* flag,
                            const void* p0, const void* p1, const void* p2, const void* p3,
                            const void* p4, const void* p5, const void* p6, const void* p7,
                            const void* p8, const void* p9, const void* p10, const void* p11,
                            const void* p12, const void* p13, const void* p14, const void* p15,
                            const void* p16, float* __restrict__ wts) {
    const void* ptrs[17] = {p0, p1, p2, p3, p4, p5, p6, p7, p8,
                            p9, p10, p11, p12, p13, p14, p15, p16};
    const int sz[17] = {5, 5, 25, 5, 320, 64, 320, 4096, 64,
                        4096, 64, 4096, 4096, 64, 320, 5, 320};
    const int off[17] = {W_GAMMA, W_BETA, W_C1PW, W_C1PB, W_C1LW, W_C1LB, W_C1RW,
                         W_C2PW, W_C2PB, W_C2LW, W_C2LB, W_C2RW,
                         W_C3PW, W_C3PB, W_C3LW, W_C3LB, W_C3RW};
    int t = blockIdx.x;
    int isf32 = *flag;
    for (int i = threadIdx.x; i < sz[t]; i += blockDim.x)
        wts[off[t] + i] = loadF(ptrs[t], i, isf32);
}

// ---------------- BN statistics ----------------
__global__ void bn_stats(const void* __restrict__ h, const int* __restrict__ flag,
                         float* __restrict__ stats) {
    int isf32 = *flag;
    float s[5] = {0, 0, 0, 0, 0}, q[5] = {0, 0, 0, 0, 0};
    int tid = blockIdx.x * blockDim.x + threadIdx.x;
    int stride = gridDim.x * blockDim.x;
    for (int i = tid; i < N_NODES; i += stride) {
#pragma unroll
        for (int f = 0; f < 5; f++) {
            float v = loadF(h, i * 5 + f, isf32);
            s[f] += v;
            q[f] += v * v;
        }
    }
#pragma unroll
    for (int f = 0; f < 5; f++) {
#pragma unroll
        for (int o = 32; o; o >>= 1) {
            s[f] += __shfl_xor(s[f], o, 64);
            q[f] += __shfl_xor(q[f], o, 64);
        }
    }
    __shared__ float ls[4][10];
    int wave = threadIdx.x >> 6, lane = threadIdx.x & 63;
    if (lane == 0) {
#pragma unroll
        for (int f = 0; f < 5; f++) { ls[wave][f] = s[f]; ls[wave][5 + f] = q[f]; }
    }
    __syncthreads();
    if (threadIdx.x < 10) {
        float v = ls[0][threadIdx.x] + ls[1][threadIdx.x] + ls[2][threadIdx.x] + ls[3][threadIdx.x];
        int idx = (threadIdx.x < 5) ? threadIdx.x : (threadIdx.x - 5 + 8);
        atomicAdd(&stats[idx], v);
    }
}

__global__ void bn_finalize(float* __restrict__ stats, const float* __restrict__ wts) {
    int f = threadIdx.x;
    if (f < 5) {
        float mean = stats[f] / (float)N_NODES;
        float var = stats[8 + f] / (float)N_NODES - mean * mean;
        float sc = wts[W_GAMMA + f] * rsqrtf(var + 1e-5f);
        stats[16 + f] = sc;
        stats[24 + f] = wts[W_BETA + f] - mean * sc;
    }
}

// ---------------- BN apply + conv1 projection (5->5) ----------------
__global__ void bn_proj1(const void* __restrict__ h, const int* __restrict__ flag,
                         const float* __restrict__ stats, const float* __restrict__ wts,
                         float* __restrict__ xbn, float* __restrict__ xp1) {
    int isf32 = *flag;
    int i = blockIdx.x * blockDim.x + threadIdx.x;
    if (i >= N_NODES) return;
    float x[5];
#pragma unroll
    for (int f = 0; f < 5; f++)
        x[f] = loadF(h, i * 5 + f, isf32) * stats[16 + f] + stats[24 + f];
#pragma unroll
    for (int f = 0; f < 5; f++) xbn[i * 5 + f] = x[f];
#pragma unroll
    for (int j = 0; j < 5; j++) {
        float a = wts[W_C1PB + j];
#pragma unroll
        for (int k = 0; k < 5; k++) a += x[k] * wts[W_C1PW + k * 5 + j];
        xp1[i * 5 + j] = fmaxf(a, 0.f);
    }
}

// ---------------- CSR build: count + within-bin position ----------------
__global__ void count_pos(const int* __restrict__ dst, int* __restrict__ deg,
                          int* __restrict__ pos) {
    int e = blockIdx.x * blockDim.x + threadIdx.x;
    if (e < N_EDGES) pos[e] = atomicAdd(&deg[dst[e]], 1);
}

// ---------------- exclusive prefix scan deg -> start (single block, wave scans) ----
__global__ void __launch_bounds__(1024) prefix_scan(const int* __restrict__ deg,
                                                    int* __restrict__ start) {
    __shared__ int s_w[16];
    __shared__ int s_carry;
    int lane = threadIdx.x & 63, wave = threadIdx.x >> 6;
    if (threadIdx.x == 0) s_carry = 0;
    __syncthreads();
    for (int base = 0; base < N_NODES; base += 1024) {
        int i = base + threadIdx.x;
        int v = (i < N_NODES) ? deg[i] : 0;
        int sc = v;
#pragma unroll
        for (int o = 1; o < 64; o <<= 1) {
            int t = __shfl_up(sc, o, 64);
            if (lane >= o) sc += t;
        }
        if (lane == 63) s_w[wave] = sc;
        __syncthreads();
        if (wave == 0) {
            int wv = (lane < 16) ? s_w[lane] : 0;
            int ws = wv;
#pragma unroll
            for (int o = 1; o < 16; o <<= 1) {
                int t = __shfl_up(ws, o, 64);
                if (lane >= o) ws += t;
            }
            if (lane < 16) s_w[lane] = ws;
        }
        __syncthreads();
        int carry = s_carry;
        int woff = (wave == 0) ? 0 : s_w[wave - 1];
        if (i < N_NODES) start[i] = carry + woff + sc - v;
        __syncthreads();
        if (threadIdx.x == 1023) s_carry = carry + s_w[15];
        __syncthreads();
    }
    if (threadIdx.x == 0) start[N_NODES] = s_carry;
}

// ---------------- scatter edges into bins: perm[p] = {src, w_bits} ----------------
__global__ void build_perm(const int* __restrict__ src, const int* __restrict__ dst,
                           const void* __restrict__ ew, const int* __restrict__ flag,
                           const int* __restrict__ start, const int* __restrict__ pos,
                           int2* __restrict__ perm) {
    int isf32 = *flag;
    int e = blockIdx.x * blockDim.x + threadIdx.x;
    if (e >= N_EDGES) return;
    int d = dst[e];
    int p = start[d] + pos[e];
    perm[p] = make_int2(src[e], __float_as_int(loadF(ew, e, isf32)));
}

// ---------------- 5-wide gather-aggregate (conv1, conv3) ----------------
__global__ void agg5(const float* __restrict__ y, const int* __restrict__ start,
                     const int2* __restrict__ perm, float* __restrict__ agg) {
    int n = blockIdx.x * blockDim.x + threadIdx.x;
    if (n >= N_NODES) return;
    int e0 = start[n], e1 = start[n + 1];
    float a0 = 0, a1 = 0, a2 = 0, a3 = 0, a4 = 0;
    for (int e = e0; e < e1; e++) {
        int2 p = perm[e];
        float w = __int_as_float(p.y);
        const float* row = y + (size_t)p.x * 5;
        a0 += row[0] * w; a1 += row[1] * w; a2 += row[2] * w;
        a3 += row[3] * w; a4 += row[4] * w;
    }
    size_t b = (size_t)n * 5;
    agg[b] = a0; agg[b + 1] = a1; agg[b + 2] = a2; agg[b + 3] = a3; agg[b + 4] = a4;
}

// ---------------- conv1 epilogue ----------------
__global__ void __launch_bounds__(256) epilogue1(const float* __restrict__ agg,
                                                 const int* __restrict__ start,
                                                 const float* __restrict__ xbn,
                                                 const float* __restrict__ wts,
                                                 float* __restrict__ x1) {
    __shared__ float s_lw[5 * 64], s_rw[5 * 64], s_lb[64];
    for (int t = threadIdx.x; t < 320; t += 256) {
        s_lw[t] = wts[W_C1LW + t];
        s_rw[t] = wts[W_C1RW + t];
    }
    if (threadIdx.x < 64) s_lb[threadIdx.x] = wts[W_C1LB + threadIdx.x];
    __syncthreads();
    int wave = threadIdx.x >> 6, lane = threadIdx.x & 63;
    int node = blockIdx.x * 4 + wave;
    if (node >= N_NODES) return;
    float ic = 1.f / fmaxf((float)(start[node + 1] - start[node]), 1.f);
    float out = s_lb[lane];
#pragma unroll
    for (int k = 0; k < 5; k++) {
        float m = agg[node * 5 + k] * ic;
        float xb = xbn[node * 5 + k];
        out += m * s_lw[k * 64 + lane] + xb * s_rw[k * 64 + lane];
    }
    float ss = out * out;
#pragma unroll
    for (int o = 32; o; o >>= 1) ss += __shfl_xor(ss, o, 64);
    float v = out / fmaxf(sqrtf(ss), 1e-12f);
    x1[(size_t)node * 64 + lane] = fmaxf(v, 0.f);
}

// ---------------- conv2 projection: y2 = relu(x1@pw2+pb2) @ lw2 ----------------
__global__ void __launch_bounds__(256) proj2(const float* __restrict__ x1,
                                             const float* __restrict__ wts,
                                             float* __restrict__ y2) {
    __shared__ float s_pw[64 * 64], s_lw[64 * 64], s_pb[64];
    for (int t = threadIdx.x; t < 4096; t += 256) {
        s_pw[t] = wts[W_C2PW + t];
        s_lw[t] = wts[W_C2LW + t];
    }
    if (threadIdx.x < 64) s_pb[threadIdx.x] = wts[W_C2PB + threadIdx.x];
    __syncthreads();
    int wave = threadIdx.x >> 6, lane = threadIdx.x & 63;
    int node = blockIdx.x * 4 + wave;
    if (node >= N_NODES) return;
    float xv = x1[(size_t)node * 64 + lane];
    float a0 = s_pb[lane];
#pragma unroll
    for (int k = 0; k < 64; k++) a0 += __shfl(xv, k, 64) * s_pw[k * 64 + lane];
    float xp = fmaxf(a0, 0.f);
    float a1 = 0.f;
#pragma unroll
    for (int k = 0; k < 64; k++) a1 += __shfl(xp, k, 64) * s_lw[k * 64 + lane];
    y2[(size_t)node * 64 + lane] = a1;
}

// ---------------- conv2: gather-aggregate + epilogue fused (x2 may alias x1) ----------
__global__ void __launch_bounds__(256) conv2_fused(const float* __restrict__ y2,
                                                   const int* __restrict__ start,
                                                   const int2* __restrict__ perm,
                                                   const float* __restrict__ x1,
                                                   const float* __restrict__ wts,
                                                   float* __restrict__ x2) {
    __shared__ float s_rw[64 * 64], s_lb[64];
    for (int t = threadIdx.x; t < 4096; t += 256) s_rw[t] = wts[W_C2RW + t];
    if (threadIdx.x < 64) s_lb[threadIdx.x] = wts[W_C2LB + threadIdx.x];
    __syncthreads();
    int wave = threadIdx.x >> 6, lane = threadIdx.x & 63;
    int node = blockIdx.x * 4 + wave;
    if (node >= N_NODES) return;
    int e0 = start[node], e1 = start[node + 1];
    float acc = 0.f;
    int e = e0;
    for (; e + 4 <= e1; e += 4) {
        int2 p0 = perm[e], p1 = perm[e + 1], p2 = perm[e + 2], p3 = perm[e + 3];
        float v0 = y2[(size_t)p0.x * 64 + lane];
        float v1 = y2[(size_t)p1.x * 64 + lane];
        float v2 = y2[(size_t)p2.x * 64 + lane];
        float v3 = y2[(size_t)p3.x * 64 + lane];
        acc += v0 * __int_as_float(p0.y) + v1 * __int_as_float(p1.y) +
               v2 * __int_as_float(p2.y) + v3 * __int_as_float(p3.y);
    }
    for (; e < e1; e++) {
        int2 p = perm[e];
        acc += y2[(size_t)p.x * 64 + lane] * __int_as_float(p.y);
    }
    float ic = 1.f / fmaxf((float)(e1 - e0), 1.f);
    float xv = x1[(size_t)node * 64 + lane];
    float out = acc * ic + s_lb[lane];
#pragma unroll
    for (int k = 0; k < 64; k++) out += __shfl(xv, k, 64) * s_rw[k * 64 + lane];
    float ss = out * out;
#pragma unroll
    for (int o = 32; o; o >>= 1) ss += __shfl_xor(ss, o, 64);
    float v = out / fmaxf(sqrtf(ss), 1e-12f);
    x2[(size_t)node * 64 + lane] = fmaxf(v, 0.f);
}

// ---------------- conv3 projection: y3 = relu(x2@pw3+pb3) @ lw3 (64->5) ----------------
__global__ void __launch_bounds__(256) proj3(const float* __restrict__ x2,
                                             const float* __restrict__ wts,
                                             float* __restrict__ y3) {
    __shared__ float s_pw[64 * 64], s_lw[64 * 5], s_pb[64];
    for (int t = threadIdx.x; t < 4096; t += 256) s_pw[t] = wts[W_C3PW + t];
    for (int t = threadIdx.x; t < 320; t += 256) s_lw[t] = wts[W_C3LW + t];
    if (threadIdx.x < 64) s_pb[threadIdx.x] = wts[W_C3PB + threadIdx.x];
    __syncthreads();
    int wave = threadIdx.x >> 6, lane = threadIdx.x & 63;
    int node = blockIdx.x * 4 + wave;
    if (node >= N_NODES) return;
    float xv = x2[(size_t)node * 64 + lane];
    float a = s_pb[lane];
#pragma unroll
    for (int k = 0; k < 64; k++) a += __shfl(xv, k, 64) * s_pw[k * 64 + lane];
    float xp = fmaxf(a, 0.f);
#pragma unroll
    for (int j = 0; j < 5; j++) {
        float p = xp * s_lw[lane * 5 + j];
#pragma unroll
        for (int o = 32; o; o >>= 1) p += __shfl_xor(p, o, 64);
        if (lane == j) y3[node * 5 + j] = p;
    }
}

// ---------------- conv3 epilogue (no relu), dtype-flexible output ----------------
__global__ void __launch_bounds__(256) epilogue3(const float* __restrict__ agg,
                                                 const int* __restrict__ start,
                                                 const float* __restrict__ x2,
                                                 const float* __restrict__ wts,
                                                 const int* __restrict__ flag,
                                                 void* __restrict__ outp) {
    __shared__ float s_rw[64 * 5];
    for (int t = threadIdx.x; t < 320; t += 256) s_rw[t] = wts[W_C3RW + t];
    __syncthreads();
    int isf32 = *flag;
    int wave = threadIdx.x >> 6, lane = threadIdx.x & 63;
    int node = blockIdx.x * 4 + wave;
    if (node >= N_NODES) return;
    float ic = 1.f / fmaxf((float)(start[node + 1] - start[node]), 1.f);
    float xv = x2[(size_t)node * 64 + lane];
    float r[5];
#pragma unroll
    for (int j = 0; j < 5; j++) {
        float p = xv * s_rw[lane * 5 + j];
#pragma unroll
        for (int o = 32; o; o >>= 1) p += __shfl_xor(p, o, 64);
        r[j] = p + agg[node * 5 + j] * ic + wts[W_C3LB + j];
    }
    float ss = 0.f;
#pragma unroll
    for (int j = 0; j < 5; j++) ss += r[j] * r[j];
    float inv = 1.f / fmaxf(sqrtf(ss), 1e-12f);
#pragma unroll
    for (int j = 0; j < 5; j++) {
        if (lane == j) {
            float v = r[j] * inv;
            if (isf32) ((float*)outp)[node * 5 + j] = v;
            else ((bf16*)outp)[node * 5 + j] = __float2bfloat16(v);
        }
    }
}

extern "C" void kernel_launch(void* const* d_in, const int* in_sizes, int n_in,
                              void* d_out, int out_size, void* d_ws, size_t ws_size,
                              hipStream_t stream) {
    const void* h = d_in[0];
    const int* ei = (const int*)d_in[1];
    const int* src = ei;
    const int* dst = ei + N_EDGES;
    const void* ew = d_in[2];

    float* W = (float*)d_ws;
    int* flag = (int*)W;                          // [0]
    float* stats = W + 16;                        // 32 floats
    float* wts = W + 64;                          // ~18k floats
    float* xbn = W + 20480;                       // N*5
    float* xp1 = xbn + N_NODES * 5;               // N*5  (later aliased by y3)
    int* deg = (int*)(xp1 + N_NODES * 5);         // N ints
    int* startp = deg + N_NODES;                  // N+1 ints (padded to +64)
    int2* perm = (int2*)(startp + N_NODES + 64);  // E int2 = 6.4M ints
    float* x1 = (float*)(perm + N_EDGES);         // N*64 f32 (first 3.2M aliased by pos)
    int* pos = (int*)x1;                          // E ints (dead before x1 written)
    float* y2 = x1 + (size_t)N_NODES * 64;        // N*64 f32 (also reused as agg buffer)
    float* x2 = x1;                               // alias: per-thread same-idx read->write
    float* y3 = xp1;                              // alias: xp1 dead after epilogue1
    float* aggbuf = y2;                           // 5-wide agg scratch (dead around proj2/after conv2)

    detect_dtype<<<1, 64, 0, stream>>>(ew, flag);
    cvt_weights<<<17, 256, 0, stream>>>(flag,
        d_in[3], d_in[4],
        d_in[5], d_in[6], d_in[7], d_in[8], d_in[9],
        d_in[10], d_in[11], d_in[12], d_in[13], d_in[14],
        d_in[15], d_in[16], d_in[17], d_in[18], d_in[19],
        wts);

    hipMemsetAsync(stats, 0, 32 * sizeof(float), stream);
    hipMemsetAsync(deg, 0, N_NODES * sizeof(int), stream);

    bn_stats<<<200, 256, 0, stream>>>(h, flag, stats);
    bn_finalize<<<1, 64, 0, stream>>>(stats, wts);
    bn_proj1<<<(N_NODES + 255) / 256, 256, 0, stream>>>(h, flag, stats, wts, xbn, xp1);

    // CSR build (once, reused by all three convs)
    count_pos<<<(N_EDGES + 255) / 256, 256, 0, stream>>>(dst, deg, pos);
    prefix_scan<<<1, 1024, 0, stream>>>(deg, startp);
    build_perm<<<(N_EDGES + 255) / 256, 256, 0, stream>>>(src, dst, ew, flag, startp, pos, perm);

    // conv1
    agg5<<<(N_NODES + 255) / 256, 256, 0, stream>>>(xp1, startp, perm, aggbuf);
    epilogue1<<<N_NODES / 4, 256, 0, stream>>>(aggbuf, startp, xbn, wts, x1);

    // conv2
    proj2<<<N_NODES / 4, 256, 0, stream>>>(x1, wts, y2);
    conv2_fused<<<N_NODES / 4, 256, 0, stream>>>(y2, startp, perm, x1, wts, x2);

    // conv3
    proj3<<<N_NODES / 4, 256, 0, stream>>>(x2, wts, y3);
    agg5<<<(N_NODES + 255) / 256, 256, 0, stream>>>(y3, startp, perm, aggbuf);
    epilogue3<<<N_NODES / 4, 256, 0, stream>>>(aggbuf, startp, x2, wts, flag, d_out);
}

// Round 5
// 877.522 us; speedup vs baseline: 3.4889x; 1.2388x over previous
//
#include <hip/hip_runtime.h>
#include <hip/hip_bf16.h>

#define N_NODES 100000
#define N_EDGES 3200000

typedef __hip_bfloat16 bf16;

// readlane broadcast: float from lane k (k compile-time constant)
#define RL(v, k) __int_as_float(__builtin_amdgcn_readlane(__float_as_int(v), (k)))

// ---- dtype-flexible load: flag==1 -> f32, flag==0 -> bf16 ----
__device__ __forceinline__ float loadF(const void* p, long long i, int isf32) {
    if (isf32) return ((const float*)p)[i];
    unsigned short v = ((const unsigned short*)p)[i];
    union { unsigned u; float f; } c;
    c.u = ((unsigned)v) << 16;
    return c.f;
}

// ---- weight canonical layout (float offsets inside wts) ----
#define W_GAMMA 0
#define W_BETA 8
#define W_C1PW 16
#define W_C1PB 48
#define W_C1LW 56
#define W_C1LB 376
#define W_C1RW 440
#define W_C2PW 760
#define W_C2PB 4856
#define W_C2LW 4920
#define W_C2LB 9016
#define W_C2RW 9080
#define W_C3PW 13176
#define W_C3PB 17272
#define W_C3LW 17336
#define W_C3LB 17656
#define W_C3RW 17664

// ---------------- dtype detection ----------------
__global__ void detect_dtype(const void* ew, int* flag) {
    const unsigned short* u = (const unsigned short*)ew;
    int lane = threadIdx.x;
    int big = 0;
    for (int i = lane; i < 1024; i += 64) {
        unsigned short v = u[2 * i];
        int ex = (v >> 7) & 0xFF;
        if (ex >= 128) big++;
    }
#pragma unroll
    for (int o = 32; o; o >>= 1) big += __shfl_xor(big, o, 64);
    if (lane == 0) *flag = (big > 100) ? 1 : 0;
}

// ---------------- convert all weight tensors to canonical fp32 ----------------
__global__ void cvt_weights(const int* flag,
                            const void* p0, const void* p1, const void* p2, const void* p3,
                            const void* p4, const void* p5, const void* p6, const void* p7,
                            const void* p8, const void* p9, const void* p10, const void* p11,
                            const void* p12, const void* p13, const void* p14, const void* p15,
                            const void* p16, float* __restrict__ wts) {
    const void* ptrs[17] = {p0, p1, p2, p3, p4, p5, p6, p7, p8,
                            p9, p10, p11, p12, p13, p14, p15, p16};
    const int sz[17] = {5, 5, 25, 5, 320, 64, 320, 4096, 64,
                        4096, 64, 4096, 4096, 64, 320, 5, 320};
    const int off[17] = {W_GAMMA, W_BETA, W_C1PW, W_C1PB, W_C1LW, W_C1LB, W_C1RW,
                         W_C2PW, W_C2PB, W_C2LW, W_C2LB, W_C2RW,
                         W_C3PW, W_C3PB, W_C3LW, W_C3LB, W_C3RW};
    int t = blockIdx.x;
    int isf32 = *flag;
    for (int i = threadIdx.x; i < sz[t]; i += blockDim.x)
        wts[off[t] + i] = loadF(ptrs[t], i, isf32);
}

// ---------------- BN statistics ----------------
__global__ void bn_stats(const void* __restrict__ h, const int* __restrict__ flag,
                         float* __restrict__ stats) {
    int isf32 = *flag;
    float s[5] = {0, 0, 0, 0, 0}, q[5] = {0, 0, 0, 0, 0};
    int tid = blockIdx.x * blockDim.x + threadIdx.x;
    int stride = gridDim.x * blockDim.x;
    for (int i = tid; i < N_NODES; i += stride) {
#pragma unroll
        for (int f = 0; f < 5; f++) {
            float v = loadF(h, i * 5 + f, isf32);
            s[f] += v;
            q[f] += v * v;
        }
    }
#pragma unroll
    for (int f = 0; f < 5; f++) {
#pragma unroll
        for (int o = 32; o; o >>= 1) {
            s[f] += __shfl_xor(s[f], o, 64);
            q[f] += __shfl_xor(q[f], o, 64);
        }
    }
    __shared__ float ls[4][10];
    int wave = threadIdx.x >> 6, lane = threadIdx.x & 63;
    if (lane == 0) {
#pragma unroll
        for (int f = 0; f < 5; f++) { ls[wave][f] = s[f]; ls[wave][5 + f] = q[f]; }
    }
    __syncthreads();
    if (threadIdx.x < 10) {
        float v = ls[0][threadIdx.x] + ls[1][threadIdx.x] + ls[2][threadIdx.x] + ls[3][threadIdx.x];
        int idx = (threadIdx.x < 5) ? threadIdx.x : (threadIdx.x - 5 + 8);
        atomicAdd(&stats[idx], v);
    }
}

__global__ void bn_finalize(float* __restrict__ stats, const float* __restrict__ wts) {
    int f = threadIdx.x;
    if (f < 5) {
        float mean = stats[f] / (float)N_NODES;
        float var = stats[8 + f] / (float)N_NODES - mean * mean;
        float sc = wts[W_GAMMA + f] * rsqrtf(var + 1e-5f);
        stats[16 + f] = sc;
        stats[24 + f] = wts[W_BETA + f] - mean * sc;
    }
}

// ---------------- BN apply + conv1 projection (5->5) ----------------
__global__ void bn_proj1(const void* __restrict__ h, const int* __restrict__ flag,
                         const float* __restrict__ stats, const float* __restrict__ wts,
                         float* __restrict__ xbn, float* __restrict__ xp1) {
    int isf32 = *flag;
    int i = blockIdx.x * blockDim.x + threadIdx.x;
    if (i >= N_NODES) return;
    float x[5];
#pragma unroll
    for (int f = 0; f < 5; f++)
        x[f] = loadF(h, i * 5 + f, isf32) * stats[16 + f] + stats[24 + f];
#pragma unroll
    for (int f = 0; f < 5; f++) xbn[i * 5 + f] = x[f];
#pragma unroll
    for (int j = 0; j < 5; j++) {
        float a = wts[W_C1PB + j];
#pragma unroll
        for (int k = 0; k < 5; k++) a += x[k] * wts[W_C1PW + k * 5 + j];
        xp1[i * 5 + j] = fmaxf(a, 0.f);
    }
}

// ---------------- CSR build: count + within-bin position ----------------
__global__ void count_pos(const int* __restrict__ dst, int* __restrict__ deg,
                          int* __restrict__ pos) {
    int e = blockIdx.x * blockDim.x + threadIdx.x;
    if (e < N_EDGES) pos[e] = atomicAdd(&deg[dst[e]], 1);
}

// ---------------- exclusive prefix scan deg -> start ----------------
__global__ void __launch_bounds__(1024) prefix_scan(const int* __restrict__ deg,
                                                    int* __restrict__ start) {
    __shared__ int s_w[16];
    __shared__ int s_carry;
    int lane = threadIdx.x & 63, wave = threadIdx.x >> 6;
    if (threadIdx.x == 0) s_carry = 0;
    __syncthreads();
    for (int base = 0; base < N_NODES; base += 1024) {
        int i = base + threadIdx.x;
        int v = (i < N_NODES) ? deg[i] : 0;
        int sc = v;
#pragma unroll
        for (int o = 1; o < 64; o <<= 1) {
            int t = __shfl_up(sc, o, 64);
            if (lane >= o) sc += t;
        }
        if (lane == 63) s_w[wave] = sc;
        __syncthreads();
        if (wave == 0) {
            int wv = (lane < 16) ? s_w[lane] : 0;
            int ws = wv;
#pragma unroll
            for (int o = 1; o < 16; o <<= 1) {
                int t = __shfl_up(ws, o, 64);
                if (lane >= o) ws += t;
            }
            if (lane < 16) s_w[lane] = ws;
        }
        __syncthreads();
        int carry = s_carry;
        int woff = (wave == 0) ? 0 : s_w[wave - 1];
        if (i < N_NODES) start[i] = carry + woff + sc - v;
        __syncthreads();
        if (threadIdx.x == 1023) s_carry = carry + s_w[15];
        __syncthreads();
    }
    if (threadIdx.x == 0) start[N_NODES] = s_carry;
}

// ---------------- scatter edges into bins: perm[p] = {src, w_bits} ----------------
__global__ void build_perm(const int* __restrict__ src, const int* __restrict__ dst,
                           const void* __restrict__ ew, const int* __restrict__ flag,
                           const int* __restrict__ start, const int* __restrict__ pos,
                           int2* __restrict__ perm) {
    int isf32 = *flag;
    int e = blockIdx.x * blockDim.x + threadIdx.x;
    if (e >= N_EDGES) return;
    int d = dst[e];
    int p = start[d] + pos[e];
    perm[p] = make_int2(src[e], __float_as_int(loadF(ew, e, isf32)));
}

// ---------------- 5-wide gather-aggregate (conv1, conv3) ----------------
__global__ void agg5(const float* __restrict__ y, const int* __restrict__ start,
                     const int2* __restrict__ perm, float* __restrict__ agg) {
    int n = blockIdx.x * blockDim.x + threadIdx.x;
    if (n >= N_NODES) return;
    int e0 = start[n], e1 = start[n + 1];
    float a0 = 0, a1 = 0, a2 = 0, a3 = 0, a4 = 0;
    for (int e = e0; e < e1; e++) {
        int2 p = perm[e];
        float w = __int_as_float(p.y);
        const float* row = y + (size_t)p.x * 5;
        a0 += row[0] * w; a1 += row[1] * w; a2 += row[2] * w;
        a3 += row[3] * w; a4 += row[4] * w;
    }
    size_t b = (size_t)n * 5;
    agg[b] = a0; agg[b + 1] = a1; agg[b + 2] = a2; agg[b + 3] = a3; agg[b + 4] = a4;
}

// ---------------- conv1 epilogue ----------------
__global__ void __launch_bounds__(256) epilogue1(const float* __restrict__ agg,
                                                 const int* __restrict__ start,
                                                 const float* __restrict__ xbn,
                                                 const float* __restrict__ wts,
                                                 float* __restrict__ x1) {
    __shared__ float s_lw[5 * 64], s_rw[5 * 64], s_lb[64];
    for (int t = threadIdx.x; t < 320; t += 256) {
        s_lw[t] = wts[W_C1LW + t];
        s_rw[t] = wts[W_C1RW + t];
    }
    if (threadIdx.x < 64) s_lb[threadIdx.x] = wts[W_C1LB + threadIdx.x];
    __syncthreads();
    int wave = threadIdx.x >> 6, lane = threadIdx.x & 63;
    int node = blockIdx.x * 4 + wave;
    if (node >= N_NODES) return;
    float ic = 1.f / fmaxf((float)(start[node + 1] - start[node]), 1.f);
    float out = s_lb[lane];
#pragma unroll
    for (int k = 0; k < 5; k++) {
        float m = agg[node * 5 + k] * ic;
        float xb = xbn[node * 5 + k];
        out += m * s_lw[k * 64 + lane] + xb * s_rw[k * 64 + lane];
    }
    float ss = out * out;
#pragma unroll
    for (int o = 32; o; o >>= 1) ss += __shfl_xor(ss, o, 64);
    float v = out / fmaxf(sqrtf(ss), 1e-12f);
    x1[(size_t)node * 64 + lane] = fmaxf(v, 0.f);
}

// ---------------- conv2 projection, weights-in-VGPR: y2 = relu(x1@pw2+pb2)@lw2 -> bf16 ----
__global__ void __launch_bounds__(256, 2) proj2_reg(const float* __restrict__ x1,
                                                    const float* __restrict__ wts,
                                                    bf16* __restrict__ y2) {
    int lane = threadIdx.x & 63;
    int wid = (blockIdx.x * blockDim.x + threadIdx.x) >> 6;
    int nw = (gridDim.x * blockDim.x) >> 6;
    float W1[64], W2[64];
#pragma unroll
    for (int k = 0; k < 64; k++) W1[k] = wts[W_C2PW + k * 64 + lane];
#pragma unroll
    for (int k = 0; k < 64; k++) W2[k] = wts[W_C2LW + k * 64 + lane];
    float pb = wts[W_C2PB + lane];
    for (int node = wid; node < N_NODES; node += nw) {
        float xv = x1[(size_t)node * 64 + lane];
        float a0 = pb, a1 = 0.f, a2 = 0.f, a3 = 0.f;
#pragma unroll
        for (int k = 0; k < 64; k += 4) {
            a0 += RL(xv, k) * W1[k];
            a1 += RL(xv, k + 1) * W1[k + 1];
            a2 += RL(xv, k + 2) * W1[k + 2];
            a3 += RL(xv, k + 3) * W1[k + 3];
        }
        float xp = fmaxf((a0 + a1) + (a2 + a3), 0.f);
        float b0 = 0.f, b1 = 0.f, b2 = 0.f, b3 = 0.f;
#pragma unroll
        for (int k = 0; k < 64; k += 4) {
            b0 += RL(xp, k) * W2[k];
            b1 += RL(xp, k + 1) * W2[k + 1];
            b2 += RL(xp, k + 2) * W2[k + 2];
            b3 += RL(xp, k + 3) * W2[k + 3];
        }
        y2[(size_t)node * 64 + lane] = __float2bfloat16((b0 + b1) + (b2 + b3));
    }
}

// ---------------- conv2: gather(bf16) + root(W-in-VGPR) + L2norm fused ----------------
__global__ void __launch_bounds__(256, 2) conv2_fused_reg(const bf16* __restrict__ y2,
                                                          const int* __restrict__ start,
                                                          const int2* __restrict__ perm,
                                                          const float* __restrict__ x1,
                                                          const float* __restrict__ wts,
                                                          float* __restrict__ x2) {
    int lane = threadIdx.x & 63;
    int wid = (blockIdx.x * blockDim.x + threadIdx.x) >> 6;
    int nw = (gridDim.x * blockDim.x) >> 6;
    float W[64];
#pragma unroll
    for (int k = 0; k < 64; k++) W[k] = wts[W_C2RW + k * 64 + lane];
    float lb = wts[W_C2LB + lane];
    for (int node = wid; node < N_NODES; node += nw) {
        int e0 = start[node], e1 = start[node + 1];
        float acc = 0.f;
        int e = e0;
        for (; e + 4 <= e1; e += 4) {
            int2 p0 = perm[e], p1 = perm[e + 1], p2 = perm[e + 2], p3 = perm[e + 3];
            float v0 = __bfloat162float(y2[(size_t)p0.x * 64 + lane]);
            float v1 = __bfloat162float(y2[(size_t)p1.x * 64 + lane]);
            float v2 = __bfloat162float(y2[(size_t)p2.x * 64 + lane]);
            float v3 = __bfloat162float(y2[(size_t)p3.x * 64 + lane]);
            acc += v0 * __int_as_float(p0.y) + v1 * __int_as_float(p1.y) +
                   v2 * __int_as_float(p2.y) + v3 * __int_as_float(p3.y);
        }
        for (; e < e1; e++) {
            int2 p = perm[e];
            acc += __bfloat162float(y2[(size_t)p.x * 64 + lane]) * __int_as_float(p.y);
        }
        float ic = 1.f / fmaxf((float)(e1 - e0), 1.f);
        float xv = x1[(size_t)node * 64 + lane];
        float o0 = acc * ic + lb, o1 = 0.f, o2 = 0.f, o3 = 0.f;
#pragma unroll
        for (int k = 0; k < 64; k += 4) {
            o0 += RL(xv, k) * W[k];
            o1 += RL(xv, k + 1) * W[k + 1];
            o2 += RL(xv, k + 2) * W[k + 2];
            o3 += RL(xv, k + 3) * W[k + 3];
        }
        float out = (o0 + o1) + (o2 + o3);
        float ss = out * out;
#pragma unroll
        for (int o = 32; o; o >>= 1) ss += __shfl_xor(ss, o, 64);
        float v = out / fmaxf(sqrtf(ss), 1e-12f);
        x2[(size_t)node * 64 + lane] = fmaxf(v, 0.f);
    }
}

// ---------------- conv3 projection, W-in-VGPR: y3 = relu(x2@pw3+pb3)@lw3 (64->5) ----------
__global__ void __launch_bounds__(256, 2) proj3_reg(const float* __restrict__ x2,
                                                    const float* __restrict__ wts,
                                                    float* __restrict__ y3) {
    int lane = threadIdx.x & 63;
    int wid = (blockIdx.x * blockDim.x + threadIdx.x) >> 6;
    int nw = (gridDim.x * blockDim.x) >> 6;
    float W1[64], Wl[5];
#pragma unroll
    for (int k = 0; k < 64; k++) W1[k] = wts[W_C3PW + k * 64 + lane];
#pragma unroll
    for (int j = 0; j < 5; j++) Wl[j] = wts[W_C3LW + lane * 5 + j];
    float pb = wts[W_C3PB + lane];
    for (int node = wid; node < N_NODES; node += nw) {
        float xv = x2[(size_t)node * 64 + lane];
        float a0 = pb, a1 = 0.f, a2 = 0.f, a3 = 0.f;
#pragma unroll
        for (int k = 0; k < 64; k += 4) {
            a0 += RL(xv, k) * W1[k];
            a1 += RL(xv, k + 1) * W1[k + 1];
            a2 += RL(xv, k + 2) * W1[k + 2];
            a3 += RL(xv, k + 3) * W1[k + 3];
        }
        float xp = fmaxf((a0 + a1) + (a2 + a3), 0.f);
#pragma unroll
        for (int j = 0; j < 5; j++) {
            float p = xp * Wl[j];
#pragma unroll
            for (int o = 32; o; o >>= 1) p += __shfl_xor(p, o, 64);
            if (lane == j) y3[node * 5 + j] = p;
        }
    }
}

// ---------------- conv3 epilogue (no relu), dtype-flexible output ----------------
__global__ void __launch_bounds__(256) epilogue3(const float* __restrict__ agg,
                                                 const int* __restrict__ start,
                                                 const float* __restrict__ x2,
                                                 const float* __restrict__ wts,
                                                 const int* __restrict__ flag,
                                                 void* __restrict__ outp) {
    __shared__ float s_rw[64 * 5];
    for (int t = threadIdx.x; t < 320; t += 256) s_rw[t] = wts[W_C3RW + t];
    __syncthreads();
    int isf32 = *flag;
    int wave = threadIdx.x >> 6, lane = threadIdx.x & 63;
    int node = blockIdx.x * 4 + wave;
    if (node >= N_NODES) return;
    float ic = 1.f / fmaxf((float)(start[node + 1] - start[node]), 1.f);
    float xv = x2[(size_t)node * 64 + lane];
    float r[5];
#pragma unroll
    for (int j = 0; j < 5; j++) {
        float p = xv * s_rw[lane * 5 + j];
#pragma unroll
        for (int o = 32; o; o >>= 1) p += __shfl_xor(p, o, 64);
        r[j] = p + agg[node * 5 + j] * ic + wts[W_C3LB + j];
    }
    float ss = 0.f;
#pragma unroll
    for (int j = 0; j < 5; j++) ss += r[j] * r[j];
    float inv = 1.f / fmaxf(sqrtf(ss), 1e-12f);
#pragma unroll
    for (int j = 0; j < 5; j++) {
        if (lane == j) {
            float v = r[j] * inv;
            if (isf32) ((float*)outp)[node * 5 + j] = v;
            else ((bf16*)outp)[node * 5 + j] = __float2bfloat16(v);
        }
    }
}

extern "C" void kernel_launch(void* const* d_in, const int* in_sizes, int n_in,
                              void* d_out, int out_size, void* d_ws, size_t ws_size,
                              hipStream_t stream) {
    const void* h = d_in[0];
    const int* ei = (const int*)d_in[1];
    const int* src = ei;
    const int* dst = ei + N_EDGES;
    const void* ew = d_in[2];

    float* W = (float*)d_ws;
    int* flag = (int*)W;                          // [0]
    float* stats = W + 16;                        // 32 floats
    float* wts = W + 64;                          // ~18k floats
    float* xbn = W + 20480;                       // N*5
    float* xp1 = xbn + N_NODES * 5;               // N*5  (later aliased by y3)
    int* deg = (int*)(xp1 + N_NODES * 5);         // N ints
    int* startp = deg + N_NODES;                  // N+1 ints (padded to +64)
    int2* perm = (int2*)(startp + N_NODES + 64);  // E int2
    float* x1 = (float*)(perm + N_EDGES);         // N*64 f32 (first 3.2M aliased by pos)
    int* pos = (int*)x1;                          // E ints (dead before x1 written)
    bf16* y2 = (bf16*)(x1 + (size_t)N_NODES * 64); // N*64 bf16
    float* aggbuf = (float*)(y2 + (size_t)N_NODES * 64); // N*5 f32
    float* x2 = x1;                               // alias: per-thread same-idx read->write
    float* y3 = xp1;                              // alias: xp1 dead after conv1

    detect_dtype<<<1, 64, 0, stream>>>(ew, flag);
    cvt_weights<<<17, 256, 0, stream>>>(flag,
        d_in[3], d_in[4],
        d_in[5], d_in[6], d_in[7], d_in[8], d_in[9],
        d_in[10], d_in[11], d_in[12], d_in[13], d_in[14],
        d_in[15], d_in[16], d_in[17], d_in[18], d_in[19],
        wts);

    hipMemsetAsync(stats, 0, 32 * sizeof(float), stream);
    hipMemsetAsync(deg, 0, N_NODES * sizeof(int), stream);

    bn_stats<<<200, 256, 0, stream>>>(h, flag, stats);
    bn_finalize<<<1, 64, 0, stream>>>(stats, wts);
    bn_proj1<<<(N_NODES + 255) / 256, 256, 0, stream>>>(h, flag, stats, wts, xbn, xp1);

    // CSR build (once, reused by all three convs)
    count_pos<<<(N_EDGES + 255) / 256, 256, 0, stream>>>(dst, deg, pos);
    prefix_scan<<<1, 1024, 0, stream>>>(deg, startp);
    build_perm<<<(N_EDGES + 255) / 256, 256, 0, stream>>>(src, dst, ew, flag, startp, pos, perm);

    // conv1
    agg5<<<(N_NODES + 255) / 256, 256, 0, stream>>>(xp1, startp, perm, aggbuf);
    epilogue1<<<N_NODES / 4, 256, 0, stream>>>(aggbuf, startp, xbn, wts, x1);

    // conv2
    proj2_reg<<<512, 256, 0, stream>>>(x1, wts, y2);
    conv2_fused_reg<<<1024, 256, 0, stream>>>(y2, startp, perm, x1, wts, x2);

    // conv3
    proj3_reg<<<512, 256, 0, stream>>>(x2, wts, y3);
    agg5<<<(N_NODES + 255) / 256, 256, 0, stream>>>(y3, startp, perm, aggbuf);
    epilogue3<<<N_NODES / 4, 256, 0, stream>>>(aggbuf, startp, x2, wts, flag, d_out);
}